// Round 10
// baseline (141.765 us; speedup 1.0000x reference)
//
#include <hip/hip_runtime.h>
#include <math.h>

// Problem: SphericalHarmonicTransform, L=8, RCUT=5, N=4194304 points.
// R10: m-SLICED GRID. The 81 per-thread accumulators are permanently live;
//     with ~35 more chain/h/Y values the body needs ~150 regs but the
//     allocator holds ~116 and rematerializes the rest every point (the
//     stable 2x gap between static and executed instr across R1-R9).
//     Split (l,m) space: blocks 0..1023 own m<=2 (39 acc), blocks 1024..2047
//     own m>=3 (42 acc); each slice streams all N points. Chain computed
//     twice (+13% total slots; slice A's chain shortens to p<=5) but
//     per-thread live set ~105 fits => no remat, and 2x blocks.
// Known-bad: launch_bounds(256,4) VGPR-clamp spill (R2); fused finalize
//     fences (R5); per-point prefetch (R4); f32x2 2-pt packing (R8).

typedef float f32x2 __attribute__((ext_vector_type(2)));

#define NL 8
#define NBLK 1024
#define NTHR 256

__device__ __forceinline__ f32x2 sp(float v) { return f32x2{v, v}; }

__device__ __forceinline__ f32x2 pkfma(f32x2 a, f32x2 b, f32x2 c) {
    return __builtin_elementwise_fma(a, b, c);
}

__device__ __forceinline__ float waveReduce(float v) {
    v += __shfl_down(v, 32);
    v += __shfl_down(v, 16);
    v += __shfl_down(v, 8);
    v += __shfl_down(v, 4);
    v += __shfl_down(v, 2);
    v += __shfl_down(v, 1);
    return v;
}

__device__ constexpr int tri_off(int m1, int m) {
    int o = 0;
    for (int k = m1; k < m; ++k) o += 9 - k;
    return o;
}
__device__ constexpr int npairs(int m1, int mhi) {
    int o = 0;
    for (int k = m1; k <= mhi; ++k) o += 9 - k;
    return o;
}

// One point for m in [MLO..MHI]. acc0 = m=0 reals (if MLO==0); accp = (re,im).
template <int MLO, int MHI>
__device__ __forceinline__ void point_body(float x, float y, float z,
                                           float* __restrict__ acc0,
                                           f32x2* __restrict__ accp) {
    constexpr int PMAX = (8 + MHI) / 2;        // chain depth needed by this slice
    constexpr int M1 = (MLO < 1) ? 1 : MLO;
    const float FACT[9] = {1.f, 1.f, 2.f, 6.f, 24.f, 120.f, 720.f, 5040.f, 40320.f};

    const float r2 = x * x + y * y + z * z;
    const bool valid = r2 > 0.0f;
    const float inv0 = __builtin_amdgcn_rsqf(r2);      // 1/sqrt(r2)
    const float norm = r2 * inv0;                      // sqrt(r2); NaN at 0, masked
    float cut = 0.5f * (__cosf(norm * 0.6283185307179586f) + 1.0f);
    cut = (r2 > 25.0f) ? 0.0f : cut;
    cut = valid ? cut : 0.0f;                          // kills NaN at r2=0
    const float inv = valid ? inv0 : 1.0f;             // safe 1/norm
    const float x0c = z * cut;

    // packed chains: lane0 = z1 (xp), lane1 = z2 (xm)
    const f32x2 w  = { -0.5f * x,  0.5f * x };         // (xpr, xmr)
    const f32x2 wi = { -0.5f * y, -0.5f * y };         // (xpi, xmi)

    // powcmplx replication:
    //  n=0 -> (1,0); n=1 -> w; n=2 -> special (r^2-i^2, 2ri);
    //  n>=3 -> buggy chain: nr = wr*br - wi*bi; ni = wr*bi + wi*nr (uses NEW nr)
    //  chain's k=2 real == special real; its (buggy) imag feeds k>=3.
    f32x2 zr[PMAX + 1], zi[PMAX + 1];
    zr[0] = sp(1.f); zi[0] = sp(0.f);
    zr[1] = w;       zi[1] = wi;
    zr[2] = w * w - wi * wi;
    zi[2] = (w + w) * wi;                              // 2*wr*wi
    {
        f32x2 cr = zr[2];
        f32x2 ci = w * wi + wi * cr;                   // buggy chain imag at k=2
#pragma unroll
        for (int k = 3; k <= PMAX; ++k) {
            const f32x2 nr = w * cr - wi * ci;
            const f32x2 ni = w * ci + wi * nr;         // buggy: uses nr
            cr = nr; ci = ni;
            zr[k] = nr; zi[k] = ni;
        }
    }

    float aa[PMAX + 1], bb[PMAX + 1], cc[PMAX + 1], dd[PMAX + 1], sqa[PMAX + 1];
#pragma unroll
    for (int p = 0; p <= PMAX; ++p) {
        aa[p] = zr[p].x;   // z1r
        cc[p] = zr[p].y;   // z2r
        bb[p] = zi[p].x;   // z1i
        dd[p] = zi[p].y;   // z2i
        sqa[p] = aa[p] * aa[p];
    }

    // h_l = x0c * inv^l
    float h[9];
    h[0] = x0c;
#pragma unroll
    for (int l = 1; l <= NL; ++l) h[l] = h[l - 1] * inv;

    // ---- m = 0 (slice A only): pure-real scalar path ----
    if constexpr (MLO == 0) {
        float Y0[5];
#pragma unroll
        for (int p = 0; p <= 4; ++p) {
            const float cpq = 1.0f / (FACT[p] * FACT[p]);
            Y0[p] = fmaf(-dd[p], dd[p], sqa[p]) * cpq;
        }
#pragma unroll
        for (int l = 0; l <= NL; ++l) {
            float sr = 0.f;
#pragma unroll
            for (int p = 0; p <= 4; ++p) {
                if (2 * p <= l) {
                    const float is = 1.0f / FACT[l - 2 * p];
                    sr = fmaf(Y0[p], is, sr);
                }
            }
            acc0[l] = fmaf(sr, h[l], acc0[l]);
        }
    }

    // ---- m in [M1..MHI]: packed (real, imag) ----
#pragma unroll
    for (int m = M1; m <= MHI; ++m) {
        f32x2 Y[PMAX + 1];
#pragma unroll
        for (int p = 0; p <= PMAX; ++p) {
            if (p >= m && 2 * p - m <= NL) {
                const int q = p - m;
                const float cpq = 1.0f / (FACT[p] * FACT[q]);
                const float bc = bb[p] * cc[q];
                const f32x2 A = { -dd[q], aa[p] };
                const f32x2 B = {  dd[q], dd[q] };
                const f32x2 C = { sqa[p], bc };
                Y[p] = pkfma(A, B, C) * sp(cpq);
            }
        }
#pragma unroll
        for (int l = m; l <= NL; ++l) {
            f32x2 s = sp(0.f);
#pragma unroll
            for (int p = 0; p <= PMAX; ++p) {
                if (p >= m && 2 * p - m <= l) {
                    const float is = 1.0f / FACT[l - 2 * p + m];
                    s = pkfma(Y[p], sp(is), s);
                }
            }
            const int ai = tri_off(M1, m) + (l - m);
            accp[ai] = pkfma(s, sp(h[l]), accp[ai]);
        }
    }
}

template <int MLO, int MHI>
__device__ __forceinline__ void run_slice(const float* __restrict__ pos,
                                          float* __restrict__ ws, int n,
                                          int bid) {
    constexpr int M1 = (MLO < 1) ? 1 : MLO;
    constexpr int NP = npairs(M1, MHI);
    constexpr int BASE = (MLO == 0) ? 9 : 0;
    constexpr int NLOC = BASE + 2 * NP;

    float acc0[(MLO == 0) ? 9 : 1];
    f32x2 accp[NP];
    if constexpr (MLO == 0) {
#pragma unroll
        for (int i = 0; i < 9; ++i) acc0[i] = 0.f;
    }
#pragma unroll
    for (int i = 0; i < NP; ++i) accp[i] = sp(0.f);

    const int t = bid * NTHR + (int)threadIdx.x;
    const int nthreads = NBLK * NTHR;                       // 262144
    const int nchunks = (n / 8 + nthreads - 1) / nthreads;  // 2 for N=2^22

    for (int c = 0; c < nchunks; ++c) {
        const int idx = (c * nthreads + t) * 8;             // 8 contiguous points
        float xs[8], ys[8], zs[8];
        if (idx + 8 <= n) {
            const float4* p4 = reinterpret_cast<const float4*>(pos + (size_t)3 * idx);
            const float4 q0 = p4[0], q1 = p4[1], q2 = p4[2];
            const float4 q3 = p4[3], q4 = p4[4], q5 = p4[5];
            xs[0] = q0.x; ys[0] = q0.y; zs[0] = q0.z;
            xs[1] = q0.w; ys[1] = q1.x; zs[1] = q1.y;
            xs[2] = q1.z; ys[2] = q1.w; zs[2] = q2.x;
            xs[3] = q2.y; ys[3] = q2.z; zs[3] = q2.w;
            xs[4] = q3.x; ys[4] = q3.y; zs[4] = q3.z;
            xs[5] = q3.w; ys[5] = q4.x; zs[5] = q4.y;
            xs[6] = q4.z; ys[6] = q4.w; zs[6] = q5.x;
            xs[7] = q5.y; ys[7] = q5.z; zs[7] = q5.w;
        } else {
#pragma unroll
            for (int k = 0; k < 8; ++k) {
                const int i = idx + k;
                const bool ok = i < n;
                xs[k] = ok ? pos[3 * i + 0] : 0.f;          // zero-pad: contributes 0
                ys[k] = ok ? pos[3 * i + 1] : 0.f;
                zs[k] = ok ? pos[3 * i + 2] : 0.f;
            }
        }
#pragma unroll
        for (int k = 0; k < 8; ++k)
            point_body<MLO, MHI>(xs[k], ys[k], zs[k], acc0, accp);
    }

    // ---- reduction: wave shuffle -> LDS across 4 waves -> per-block row ----
    __shared__ float red[NLOC][5];
    const int lane = threadIdx.x & 63;
    const int wave = threadIdx.x >> 6;

    if constexpr (MLO == 0) {
#pragma unroll
        for (int l = 0; l <= NL; ++l) {
            float vr = waveReduce(acc0[l]);
            if (lane == 0) red[l][wave] = vr;
        }
    }
#pragma unroll
    for (int m = M1; m <= MHI; ++m) {
#pragma unroll
        for (int l = m; l <= NL; ++l) {
            const int pi = tri_off(M1, m) + (l - m);
            float vr = waveReduce(accp[pi].x);
            if (lane == 0) red[BASE + 2 * pi + 0][wave] = vr;
            float vi = waveReduce(accp[pi].y);
            if (lane == 0) red[BASE + 2 * pi + 1][wave] = vi;
        }
    }
    __syncthreads();

    // each local slot -> its global output slot; only owned slots written
    if ((int)threadIdx.x < NLOC) {
        const int tid = threadIdx.x;
        float s = 0.f;
#pragma unroll
        for (int w = 0; w < 4; ++w) s += red[tid][w];
        int j;
        if (MLO == 0 && tid < 9) {
            j = tid * tid + tid;                            // m=0: slot l^2+l
        } else {
            int r = tid - BASE;
            int pairIdx = r >> 1;
            const bool im = r & 1;
            int m = M1, rem = pairIdx;
            while (rem >= 9 - m) { rem -= 9 - m; ++m; }
            const int l = m + rem;
            j = l * l + l + (im ? -m : m);
        }
        ws[(size_t)j * NBLK + bid] = s;
    }
}

__global__ __launch_bounds__(256, 2)
void sht_main(const float* __restrict__ pos, float* __restrict__ ws, int n) {
    if (blockIdx.x < NBLK)
        run_slice<0, 2>(pos, ws, n, blockIdx.x);
    else
        run_slice<3, 8>(pos, ws, n, blockIdx.x - NBLK);
}

__device__ double dfact(int nn) {
    double r = 1.0;
    for (int i = 2; i <= nn; ++i) r *= (double)i;
    return r;
}

// one block per output slot; 256 threads sum 1024 coalesced partials
__global__ __launch_bounds__(256)
void sht_finalize(const float* __restrict__ ws, float* __restrict__ out) {
    const int j = blockIdx.x;       // 0..80
    const int t = threadIdx.x;
    float s = 0.f;
#pragma unroll
    for (int k = 0; k < NBLK / 256; ++k)
        s += ws[(size_t)j * NBLK + k * 256 + t];
    s = waveReduce(s);

    __shared__ float red[4];
    const int lane = t & 63, wave = t >> 6;
    if (lane == 0) red[wave] = s;
    __syncthreads();
    if (t == 0) {
        float tot = red[0] + red[1] + red[2] + red[3];
        int l = 0;
        while ((l + 1) * (l + 1) <= j) ++l;
        const int M = j - l * l - l;
        const int m = (M < 0) ? -M : M;
        // f = sqrt((l+m)!(l-m)!); k_l = sqrt((2l+1)/(4*3.14159))  (ref PI=3.14159)
        double sc = sqrt(dfact(l + m) * dfact(l - m)) *
                    sqrt((double)(2 * l + 1) / (4.0 * 3.14159));
        if (m > 0) sc *= sqrt(2.0) * ((m & 1) ? -1.0 : 1.0);
        out[j] = (float)((double)tot * sc);
    }
}

extern "C" void kernel_launch(void* const* d_in, const int* in_sizes, int n_in,
                              void* d_out, int out_size, void* d_ws, size_t ws_size,
                              hipStream_t stream) {
    const float* pos = (const float*)d_in[0];
    const int npts = in_sizes[0] / 3;
    float* ws = (float*)d_ws;
    float* out = (float*)d_out;

    sht_main<<<2 * NBLK, NTHR, 0, stream>>>(pos, ws, npts);
    sht_finalize<<<81, 256, 0, stream>>>(ws, out);
}

// Round 11
// 138.500 us; speedup vs baseline: 1.0236x; 1.0236x over previous
//
#include <hip/hip_runtime.h>
#include <math.h>

// Problem: SphericalHarmonicTransform, L=8, RCUT=5, N=4194304 points.
// R11: T-DIRECT scalar formulation. Model locked in R10 post-mortem: kernel is
//     VALU-issue-bound (VALUBusy ~50% == the counter's ceiling for wave64 on
//     SIMD-32); wall time tracks total issued instructions in every round.
//     So: delete the Y stage (existed only to shrink the constant alphabet —
//     unnecessary: v_fmac_f32 is VOP2, takes a 32-bit literal in src0, so
//     `s += c*T` with a unique constant is ONE issue) and drop all f32x2
//     marshalling in the m-stage (R9's {-d,a}/{d,d}/{sqa,bc} pair-builds cost
//     ~60 v_movs/pt). Keep f32x2 only for the clean z1||z2 chains.
//     ~408 single-issue ops/pt vs R9's ~510 effective.
// Known-bad: launch_bounds(256,4) VGPR-clamp spill (R2); fused finalize
//     fences (R5); per-point prefetch (R4); 2-pt f32x2 packing (R8);
//     m-sliced grid (R10, +instr => +time).

typedef float f32x2 __attribute__((ext_vector_type(2)));

#define NL 8
#define NBLK 1024
#define NTHR 256

__device__ __forceinline__ f32x2 sp(float v) { return f32x2{v, v}; }

__device__ __forceinline__ float waveReduce(float v) {
    v += __shfl_down(v, 32);
    v += __shfl_down(v, 16);
    v += __shfl_down(v, 8);
    v += __shfl_down(v, 4);
    v += __shfl_down(v, 2);
    v += __shfl_down(v, 1);
    return v;
}

// One point, fully unrolled. acc0[9] = m=0; accr/acci[36] = m>=1 (tri index).
__device__ __forceinline__ void point_body(float x, float y, float z,
                                           float* __restrict__ acc0,
                                           float* __restrict__ accr,
                                           float* __restrict__ acci) {
    const float FACT[9] = {1.f, 1.f, 2.f, 6.f, 24.f, 120.f, 720.f, 5040.f, 40320.f};

    const float r2 = x * x + y * y + z * z;
    const bool valid = r2 > 0.0f;
    const float inv0 = __builtin_amdgcn_rsqf(r2);      // 1/sqrt(r2)
    const float norm = r2 * inv0;                      // sqrt(r2); NaN at 0, masked
    float cut = 0.5f * (__cosf(norm * 0.6283185307179586f) + 1.0f);
    cut = (r2 > 25.0f) ? 0.0f : cut;
    cut = valid ? cut : 0.0f;                          // kills NaN at r2=0
    const float inv = valid ? inv0 : 1.0f;             // safe 1/norm
    const float x0c = z * cut;

    // packed chains: lane0 = z1 (xp), lane1 = z2 (xm)
    const f32x2 w  = { -0.5f * x,  0.5f * x };         // (xpr, xmr)
    const f32x2 wi = { -0.5f * y, -0.5f * y };         // (xpi, xmi)

    // powcmplx replication:
    //  n=0 -> (1,0); n=1 -> w; n=2 -> special (r^2-i^2, 2ri);
    //  n>=3 -> buggy chain: nr = wr*br - wi*bi; ni = wr*bi + wi*nr (uses NEW nr)
    //  chain's k=2 real == special real; its (buggy) imag feeds k>=3.
    f32x2 zr[9], zi[9];
    zr[0] = sp(1.f); zi[0] = sp(0.f);
    zr[1] = w;       zi[1] = wi;
    zr[2] = w * w - wi * wi;
    zi[2] = (w + w) * wi;                              // 2*wr*wi
    {
        f32x2 cr = zr[2];
        f32x2 ci = w * wi + wi * cr;                   // buggy chain imag at k=2
#pragma unroll
        for (int k = 3; k <= NL; ++k) {
            const f32x2 nr = w * cr - wi * ci;
            const f32x2 ni = w * ci + wi * nr;         // buggy: uses nr
            cr = nr; ci = ni;
            zr[k] = nr; zi[k] = ni;
        }
    }

    // unpack views (aliases of chain registers) + sqa
    float aa[9], bb[9], cc[9], dd[9], sqa[9];
#pragma unroll
    for (int p = 0; p <= NL; ++p) {
        aa[p] = zr[p].x;   // z1r
        cc[p] = zr[p].y;   // z2r
        bb[p] = zi[p].x;   // z1i
        dd[p] = zi[p].y;   // z2i
        sqa[p] = aa[p] * aa[p];
    }

    // h_l = x0c * inv^l  (cutoff + 1/r^l deferred out of the sums)
    float h[9];
    h[0] = x0c;
#pragma unroll
    for (int l = 1; l <= NL; ++l) h[l] = h[l - 1] * inv;

    // T(p,q) directly (ref: tr = z1r^2 - z2i^2 !), scalar, no constants folded:
    float Tr[9][9], Ti[9][9];
#pragma unroll
    for (int p = 0; p <= NL; ++p) {
#pragma unroll
        for (int q = 0; q <= NL; ++q) {
            if (q <= p && p + q <= NL) {
                Tr[p][q] = fmaf(-dd[q], dd[q], sqa[p]);
                if (q != p)                          // p==q feeds only m=0 real
                    Ti[p][q] = fmaf(aa[p], dd[q], bb[p] * cc[q]);
            }
        }
    }

    // sums with FULL constants c = 1/(p! q! s!) as literal fmac (1 issue each):
    // acc(l,m) += h_l * sum_p c * T(p, p-m)
#pragma unroll
    for (int l = 0; l <= NL; ++l) {
#pragma unroll
        for (int m = 0; m <= l; ++m) {
            float sr = 0.f, si = 0.f;
#pragma unroll
            for (int p = 0; p <= NL; ++p) {
                if (p >= m && 2 * p - m <= l) {
                    const int q = p - m;
                    const int s = l - 2 * p + m;
                    const float c = 1.0f / (FACT[p] * FACT[q] * FACT[s]);
                    sr = fmaf(Tr[p][q], c, sr);      // v_fmac_f32 w/ literal
                    if (m > 0) si = fmaf(Ti[p][q], c, si);
                }
            }
            if (m == 0) {
                acc0[l] = fmaf(sr, h[l], acc0[l]);
            } else {
                const int ai = l * (l - 1) / 2 + (m - 1);   // tri index, m>=1
                accr[ai] = fmaf(sr, h[l], accr[ai]);
                acci[ai] = fmaf(si, h[l], acci[ai]);
            }
        }
    }
}

__global__ __launch_bounds__(256, 1)   // allocator free; occupancy non-binding
void sht_main(const float* __restrict__ pos, float* __restrict__ ws, int n) {
    float acc0[9], accr[36], acci[36];
#pragma unroll
    for (int i = 0; i < 9; ++i) acc0[i] = 0.f;
#pragma unroll
    for (int i = 0; i < 36; ++i) { accr[i] = 0.f; acci[i] = 0.f; }

    const int t = blockIdx.x * NTHR + threadIdx.x;
    const int nthreads = NBLK * NTHR;                       // 262144
    const int nchunks = (n / 8 + nthreads - 1) / nthreads;  // 2 for N=2^22

    for (int c = 0; c < nchunks; ++c) {
        const int idx = (c * nthreads + t) * 8;             // 8 contiguous points
        float xs[8], ys[8], zs[8];
        if (idx + 8 <= n) {
            const float4* p4 = reinterpret_cast<const float4*>(pos + (size_t)3 * idx);
            const float4 q0 = p4[0], q1 = p4[1], q2 = p4[2];
            const float4 q3 = p4[3], q4 = p4[4], q5 = p4[5];
            xs[0] = q0.x; ys[0] = q0.y; zs[0] = q0.z;
            xs[1] = q0.w; ys[1] = q1.x; zs[1] = q1.y;
            xs[2] = q1.z; ys[2] = q1.w; zs[2] = q2.x;
            xs[3] = q2.y; ys[3] = q2.z; zs[3] = q2.w;
            xs[4] = q3.x; ys[4] = q3.y; zs[4] = q3.z;
            xs[5] = q3.w; ys[5] = q4.x; zs[5] = q4.y;
            xs[6] = q4.z; ys[6] = q4.w; zs[6] = q5.x;
            xs[7] = q5.y; ys[7] = q5.z; zs[7] = q5.w;
        } else {
#pragma unroll
            for (int k = 0; k < 8; ++k) {
                const int i = idx + k;
                const bool ok = i < n;
                xs[k] = ok ? pos[3 * i + 0] : 0.f;          // zero-pad: contributes 0
                ys[k] = ok ? pos[3 * i + 1] : 0.f;
                zs[k] = ok ? pos[3 * i + 2] : 0.f;
            }
        }
#pragma unroll
        for (int k = 0; k < 8; ++k)
            point_body(xs[k], ys[k], zs[k], acc0, accr, acci);
    }

    // ---- reduction: wave shuffle -> LDS across 4 waves -> per-block row ----
    __shared__ float red[81][5];   // [out slot][wave], padded stride
    const int lane = threadIdx.x & 63;
    const int wave = threadIdx.x >> 6;

#pragma unroll
    for (int l = 0; l <= NL; ++l) {
        float vr = waveReduce(acc0[l]);
        if (lane == 0) red[l * l + l][wave] = vr;
    }
#pragma unroll
    for (int m = 1; m <= NL; ++m) {
#pragma unroll
        for (int l = m; l <= NL; ++l) {
            const int ai = l * (l - 1) / 2 + (m - 1);
            float vr = waveReduce(accr[ai]);
            if (lane == 0) red[l * l + l + m][wave] = vr;
            float vi = waveReduce(acci[ai]);
            if (lane == 0) red[l * l + l - m][wave] = vi;
        }
    }
    __syncthreads();

    // transposed partials: ws[slot*NBLK + block] -> coalesced finalize reads
    if ((int)threadIdx.x < 81) {
        float s = 0.f;
#pragma unroll
        for (int w = 0; w < 4; ++w) s += red[threadIdx.x][w];
        ws[(size_t)threadIdx.x * NBLK + blockIdx.x] = s;
    }
}

__device__ double dfact(int nn) {
    double r = 1.0;
    for (int i = 2; i <= nn; ++i) r *= (double)i;
    return r;
}

// one block per output slot; 256 threads sum 1024 coalesced partials
__global__ __launch_bounds__(256)
void sht_finalize(const float* __restrict__ ws, float* __restrict__ out) {
    const int j = blockIdx.x;       // 0..80
    const int t = threadIdx.x;
    float s = 0.f;
#pragma unroll
    for (int k = 0; k < NBLK / 256; ++k)
        s += ws[(size_t)j * NBLK + k * 256 + t];
    s = waveReduce(s);

    __shared__ float red[4];
    const int lane = t & 63, wave = t >> 6;
    if (lane == 0) red[wave] = s;
    __syncthreads();
    if (t == 0) {
        float tot = red[0] + red[1] + red[2] + red[3];
        int l = 0;
        while ((l + 1) * (l + 1) <= j) ++l;
        const int M = j - l * l - l;
        const int m = (M < 0) ? -M : M;
        // f = sqrt((l+m)!(l-m)!); k_l = sqrt((2l+1)/(4*3.14159))  (ref PI=3.14159)
        double sc = sqrt(dfact(l + m) * dfact(l - m)) *
                    sqrt((double)(2 * l + 1) / (4.0 * 3.14159));
        if (m > 0) sc *= sqrt(2.0) * ((m & 1) ? -1.0 : 1.0);
        out[j] = (float)((double)tot * sc);
    }
}

extern "C" void kernel_launch(void* const* d_in, const int* in_sizes, int n_in,
                              void* d_out, int out_size, void* d_ws, size_t ws_size,
                              hipStream_t stream) {
    const float* pos = (const float*)d_in[0];
    const int npts = in_sizes[0] / 3;
    float* ws = (float*)d_ws;
    float* out = (float*)d_out;

    sht_main<<<NBLK, NTHR, 0, stream>>>(pos, ws, npts);
    sht_finalize<<<81, 256, 0, stream>>>(ws, out);
}